// Round 8
// baseline (265.952 us; speedup 1.0000x reference)
//
#include <hip/hip_runtime.h>
#include <math.h>

#define NG 800000
#define NCH 12500        // 64-row chunks

typedef __attribute__((ext_vector_type(8))) short short8;
typedef __attribute__((ext_vector_type(4))) float f32x4;

__device__ __forceinline__ float sis(float t) {
    t = fminf(fmaxf(t, 0.01f), 0.99f);
    return logf(t / (1.0f - t));
}
__device__ __forceinline__ unsigned short f2bf(float f) {
    unsigned int u = __float_as_uint(f);
    return (unsigned short)((u + 0x7FFFu + ((u >> 16) & 1u)) >> 16);
}
__device__ __forceinline__ unsigned int cvtpk(float a, float b) {
    unsigned int r;
    asm("v_cvt_pk_bf16_f32 %0, %1, %2" : "=v"(r) : "v"(a), "v"(b));
    return r;
}
union S8 { uint4 q; short8 v; };

// ===========================================================================
// Kernel A: geometry. Coalesced LDS-staged I/O (verified round-4 structure)
// + packed 64B/row image into ws: {df0,df1,mask,pad | 24x bf16 anchor}.
// ===========================================================================
__global__ __launch_bounds__(256) void k_geom(
    const float* __restrict__ gp,
    const float* __restrict__ zbuf,
    const float* __restrict__ w2c,
    const float* __restrict__ ck,
    const float* __restrict__ vo,
    const float* __restrict__ ss,
    const float* __restrict__ cvr,
    float* __restrict__ oA, float* __restrict__ oT,
    float* __restrict__ oP, float* __restrict__ oM,
    char* __restrict__ wpk)
{
    __shared__ __align__(16) float sB[256 * 25];
    __shared__ __align__(16) float sA[256 * 23];

    const long base = (long)blockIdx.x * 256;
    const int t = threadIdx.x;

    {
        const float4* src = (const float4*)(gp + base * 25);
        float4* dst = (float4*)sB;
        for (int k = t; k < 1600; k += 256) dst[k] = src[k];
    }
    __syncthreads();

    float v[25];
    #pragma unroll
    for (int j = 0; j < 25; ++j) v[j] = sB[t * 25 + j];

    float R00=w2c[0],R01=w2c[1],R02=w2c[2],T0=w2c[3];
    float R10=w2c[4],R11=w2c[5],R12=w2c[6],T1=w2c[7];
    float R20=w2c[8],R21=w2c[9],R22=w2c[10],T2=w2c[11];
    float x=v[0], y=v[1], zz=v[2];
    float c0 = R00*x + R01*y + R02*zz + T0;
    float c1 = R10*x + R11*y + R12*zz + T1;
    float c2 = R20*x + R21*y + R22*zz + T2;

    bool m1 = c2 > 1e-6f;
    float zc = m1 ? c2 : 1e-6f;
    float fpx = ck[0] * c0 / zc + ck[2];
    float fpy = ck[4] * c1 / zc + ck[5];
    bool m2 = (fpx >= 0.f) && (fpx < 640.f) && (fpy >= 0.f) && (fpy < 480.f);
    bool mall = m1 && m2;

    float n0=vo[0]+1e-3f, n1=vo[1]+1e-3f, n2=vo[2]+1e-3f;
    float f0=vo[0]+ss[0]-1e-3f, f1=vo[1]+ss[1]-1e-3f, f2=vo[2]+ss[2]-1e-3f;
    bool gpm = (x>n0)&&(x<f0)&&(y>n1)&&(y<f1)&&(zz>n2)&&(zz<f2);
    bool mdet = mall && gpm;

    sB[t * 25 + 24] = gpm ? 1.0f : v[24];

    float tag = (v[23] == 1.0f) ? 0.5f : 0.0f;
    if (!mdet) tag = 1.0f;

    bool gm = (c0>=cvr[0])&&(c0<=cvr[3])&&(c1>=cvr[1])&&(c1<=cvr[4])&&(c2>=cvr[2])&&(c2<=cvr[5]);
    bool reuse = gpm && gm;

    const long i = base + t;
    oM[i] = reuse ? 1.0f : 0.0f;
    oT[i] = reuse ? tag : 0.0f;

    // df (cz_safe semantics)
    float czs = (fabsf(c2) < 1e-6f) ? 1e-6f : c2;
    float px2 = ck[0]*c0/czs + ck[2];
    float py2 = ck[4]*c1/czs + ck[5];
    int ixq = (int)fminf(fmaxf(px2, 0.f), 639.f);
    int iyq = (int)fminf(fmaxf(py2, 0.f), 479.f);
    float dz = zbuf[iyq*640 + ixq];

    // anchor in registers
    float ar[23];
    if (reuse) {
        float tr = R00 + R11 + R22;
        float qw = sqrtf(fmaxf(tr + 1.0f, 1e-8f)) * 0.5f;
        float inv4 = 0.25f / qw;
        float qx = (R21-R12)*inv4, qy=(R02-R20)*inv4, qz=(R10-R01)*inv4;
        float p0=v[6], p1=v[7], p2=v[8], p3=v[9];
        ar[0] = sis((c0 - cvr[0]) / (cvr[3]-cvr[0]));
        ar[1] = sis((c1 - cvr[1]) / (cvr[4]-cvr[1]));
        ar[2] = sis((c2 - cvr[2]) / (cvr[5]-cvr[2]));
        ar[3] = sis(v[3]); ar[4] = sis(v[4]); ar[5] = sis(v[5]);
        ar[6] = qw*p0 - qx*p1 - qy*p2 - qz*p3;
        ar[7] = qw*p1 + qx*p0 + qy*p3 - qz*p2;
        ar[8] = qw*p2 - qx*p3 + qy*p0 + qz*p1;
        ar[9] = qw*p3 + qx*p2 - qy*p1 + qz*p0;
        ar[10] = sis(v[10]);
        #pragma unroll
        for (int j = 0; j < 12; ++j) ar[11 + j] = v[11 + j];
    } else {
        #pragma unroll
        for (int j = 0; j < 23; ++j) ar[j] = 0.0f;
    }
    #pragma unroll
    for (int j = 0; j < 23; ++j) sA[t * 23 + j] = ar[j];

    // packed 64B row
    {
        char* pw = wpk + (long)i * 64;
        uint4 u0, u1, u2, u3;
        u0.x = __float_as_uint(dz);
        u0.y = __float_as_uint(c2);
        u0.z = __float_as_uint(reuse ? 1.0f : 0.0f);
        u0.w = 0u;
        u1.x=cvtpk(ar[0],ar[1]);   u1.y=cvtpk(ar[2],ar[3]);
        u1.z=cvtpk(ar[4],ar[5]);   u1.w=cvtpk(ar[6],ar[7]);
        u2.x=cvtpk(ar[8],ar[9]);   u2.y=cvtpk(ar[10],ar[11]);
        u2.z=cvtpk(ar[12],ar[13]); u2.w=cvtpk(ar[14],ar[15]);
        u3.x=cvtpk(ar[16],ar[17]); u3.y=cvtpk(ar[18],ar[19]);
        u3.z=cvtpk(ar[20],ar[21]); u3.w=cvtpk(ar[22],0.0f);
        *(uint4*)(pw)      = u0;
        *(uint4*)(pw + 16) = u1;
        *(uint4*)(pw + 32) = u2;
        *(uint4*)(pw + 48) = u3;
    }
    __syncthreads();

    {
        const float4* s = (const float4*)sB;
        float4* d = (float4*)(oP + base * 25);
        for (int k = t; k < 1600; k += 256) d[k] = s[k];
        const float4* s2 = (const float4*)sA;
        float4* d2 = (float4*)(oA + base * 23);
        for (int k = t; k < 1472; k += 256) d2[k] = s2[k];
    }
}

// ===========================================================================
// Kernel B: MFMA MLP. 512 thr (8 waves), 2 blocks/CU (80.2 KB LDS),
// VGPR<=128. Per-wave 64-row chunks, work-stealing. All per-row state from
// the packed image (16B header + 16B anchor granule per lane).
// ===========================================================================
#define W2T_OFF 0        // 16384
#define W3T_OFF 16384    // 24576
#define WIT_OFF 40960    //  4608  [c=96][k=24] bf16 (48B rows)
#define B2_OFF  45568    //   512
#define BC_OFF  46080    //   384
#define W1I_OFF 46464    //  1024  float4[64] = (W1[0][k], W1[1][k], b1[k], 0)
#define WV_OFF  47488    // 8 waves x 4096 (H2 strip)
#define LDS_B   (WV_OFF + 8 * 4096)   // 80256
#define GRIDB   512
#define NSTATIC 4096     // GRIDB * 8 waves

__global__ __launch_bounds__(512, 4) void k_mlp(
    const float* __restrict__ W1, const float* __restrict__ b1,
    const float* __restrict__ W2, const float* __restrict__ b2,
    const float* __restrict__ W3, const float* __restrict__ b3,
    const float* __restrict__ Wi, const float* __restrict__ bi,
    const char* __restrict__ wpk,
    float* __restrict__ oI,
    int* __restrict__ ctr)
{
    __shared__ __align__(16) char lds[LDS_B];
    float* sB2 = (float*)(lds + B2_OFF);
    float* sBC = (float*)(lds + BC_OFF);
    const float4* sW1 = (const float4*)(lds + W1I_OFF);

    const int t  = threadIdx.x;
    const int wv = t >> 6;
    const int l  = t & 63;
    const int la = l & 15;
    const int lb = l >> 4;
    char* wlds = lds + WV_OFF + wv * 4096;

    for (int idx = t; idx < 8192; idx += 512) {            // W2T
        int k = idx >> 7, c = idx & 127;
        *(unsigned short*)(lds + W2T_OFF + c*128 + (((k>>3) ^ (c&7))<<4) + (k&7)*2)
            = f2bf(W2[idx]);
    }
    for (int idx = t; idx < 12288; idx += 512) {           // W3T
        int k = idx / 96, c = idx - k*96;
        *(unsigned short*)(lds + W3T_OFF + c*256 + (((k>>3) ^ (c&15))<<4) + (k&7)*2)
            = f2bf(W3[idx]);
    }
    for (int idx = t; idx < 2304; idx += 512) {            // WIT
        int c = idx / 24, k = idx - c*24;
        *(unsigned short*)(lds + WIT_OFF + c*48 + k*2) = f2bf(Wi[k*96 + c]);
    }
    if (t < 128) sB2[t] = b2[t];
    if (t < 96)  sBC[t] = b3[t] + bi[t];
    if (t < 64)  ((float4*)(lds + W1I_OFF))[t] = make_float4(W1[t], W1[64+t], b1[t], 0.f);

    __syncthreads();   // only block barrier

    int n = blockIdx.x * 8 + wv;
    while (n < NCH) {
        const long Rb = (long)n * 64;

        #pragma unroll 1
        for (int s = 0; s < 4; ++s) {
            const int rsrc = 16*s + la;
            const char* prow = wpk + (Rb + rsrc) * 64;
            uint4 hd = *(const uint4*)(prow);
            float d0s = __uint_as_float(hd.x);
            float d1s = __uint_as_float(hd.y);
            float mks = __uint_as_float(hd.z);
            S8 bAu;
            if (lb < 3) bAu.q = *(const uint4*)(prow + 16 + lb*16);
            else        bAu.q = make_uint4(0,0,0,0);

            // h1 in-lane: k = lb*8+j and 32+lb*8+j
            S8 hb0u, hb1u;
            {
                const int kb = lb * 8;
                float h[8], h2[8];
                #pragma unroll
                for (int j = 0; j < 8; ++j) {
                    float4 w = sW1[kb + j];
                    h[j] = fmaxf(fmaf(d0s, w.x, fmaf(d1s, w.y, w.z)), 0.f);
                }
                #pragma unroll
                for (int j = 0; j < 8; ++j) {
                    float4 w = sW1[32 + kb + j];
                    h2[j] = fmaxf(fmaf(d0s, w.x, fmaf(d1s, w.y, w.z)), 0.f);
                }
                hb0u.q.x = cvtpk(h[0],h[1]);   hb0u.q.y = cvtpk(h[2],h[3]);
                hb0u.q.z = cvtpk(h[4],h[5]);   hb0u.q.w = cvtpk(h[6],h[7]);
                hb1u.q.x = cvtpk(h2[0],h2[1]); hb1u.q.y = cvtpk(h2[2],h2[3]);
                hb1u.q.z = cvtpk(h2[4],h2[5]); hb1u.q.w = cvtpk(h2[6],h2[7]);
            }

            // GEMM1 -> H2 strip (per-wave LDS)
            {
                #pragma unroll
                for (int ct = 0; ct < 8; ++ct) {
                    const int cc = ct*16 + la;
                    short8 w0 = *(short8*)(lds + W2T_OFF + cc*128 + (((lb  ) ^ (cc&7))<<4));
                    short8 w1v= *(short8*)(lds + W2T_OFF + cc*128 + (((lb+4) ^ (cc&7))<<4));
                    f32x4 acc = {0.f, 0.f, 0.f, 0.f};
                    acc = __builtin_amdgcn_mfma_f32_16x16x32_bf16(w0, hb0u.v, acc, 0, 0, 0);
                    acc = __builtin_amdgcn_mfma_f32_16x16x32_bf16(w1v, hb1u.v, acc, 0, 0, 0);
                    float4 bb = *(float4*)&sB2[ct*16 + lb*4];
                    float e0 = fmaxf(acc[0] + bb.x, 0.f);
                    float e1 = fmaxf(acc[1] + bb.y, 0.f);
                    float e2 = fmaxf(acc[2] + bb.z, 0.f);
                    float e3 = fmaxf(acc[3] + bb.w, 0.f);
                    uint2 pk; pk.x = cvtpk(e0, e1); pk.y = cvtpk(e2, e3);
                    const int gg = ct*2 + (lb>>1);
                    *(uint2*)(wlds + la*256 + ((gg ^ la)<<4) + (lb&1)*8) = pk;
                }
            }

            // GEMM2 -> oI
            {
                short8 B0 = *(short8*)(wlds + la*256 + ((( 0 + lb) ^ la)<<4));
                short8 B1 = *(short8*)(wlds + la*256 + ((( 4 + lb) ^ la)<<4));
                short8 B2v= *(short8*)(wlds + la*256 + ((( 8 + lb) ^ la)<<4));
                short8 B3 = *(short8*)(wlds + la*256 + (((12 + lb) ^ la)<<4));
                float* orow = oI + (Rb + rsrc) * 96;
                #pragma unroll
                for (int ct = 0; ct < 6; ++ct) {
                    const int cc = ct*16 + la;
                    f32x4 acc = {0.f, 0.f, 0.f, 0.f};
                    short8 A0 = *(short8*)(lds + W3T_OFF + cc*256 + ((( 0 + lb) ^ (cc&15))<<4));
                    short8 A1 = *(short8*)(lds + W3T_OFF + cc*256 + ((( 4 + lb) ^ (cc&15))<<4));
                    short8 A2 = *(short8*)(lds + W3T_OFF + cc*256 + ((( 8 + lb) ^ (cc&15))<<4));
                    short8 A3 = *(short8*)(lds + W3T_OFF + cc*256 + (((12 + lb) ^ (cc&15))<<4));
                    acc = __builtin_amdgcn_mfma_f32_16x16x32_bf16(A0, B0, acc, 0, 0, 0);
                    acc = __builtin_amdgcn_mfma_f32_16x16x32_bf16(A1, B1, acc, 0, 0, 0);
                    acc = __builtin_amdgcn_mfma_f32_16x16x32_bf16(A2, B2v, acc, 0, 0, 0);
                    acc = __builtin_amdgcn_mfma_f32_16x16x32_bf16(A3, B3, acc, 0, 0, 0);
                    short8 Aw;
                    if (lb < 3) Aw = *(short8*)(lds + WIT_OFF + cc*48 + lb*16);
                    else { S8 z; z.q = make_uint4(0,0,0,0); Aw = z.v; }
                    acc = __builtin_amdgcn_mfma_f32_16x16x32_bf16(Aw, bAu.v, acc, 0, 0, 0);
                    float4 bb = *(float4*)&sBC[ct*16 + lb*4];
                    float4 o;
                    o.x = (mks != 0.f) ? acc[0] + bb.x : 0.f;
                    o.y = (mks != 0.f) ? acc[1] + bb.y : 0.f;
                    o.z = (mks != 0.f) ? acc[2] + bb.z : 0.f;
                    o.w = (mks != 0.f) ? acc[3] + bb.w : 0.f;
                    *(float4*)(orow + ct*16 + lb*4) = o;
                }
            }
        }

        // work-stealing next chunk (chunks disjoint -> deterministic)
        int nn = 0;
        if (l == 0) nn = atomicAdd(ctr, 1);
        n = NSTATIC + __shfl(nn, 0);
    }
}

// ===========================================================================
// Fallback (round-6 fused kernel) if ws is too small for the packed image.
// ===========================================================================
#define FB_W2T 0
#define FB_W3T 16384
#define FB_WIT 40960
#define FB_B2  45568
#define FB_BC  46080
#define FB_W1I 46464
#define FB_WV  47488
#define FB_H2S 0
#define FB_ANB 4096
#define FB_WSZ 8192
#define FB_TOT (FB_WV + 8 * FB_WSZ)

__global__ __launch_bounds__(512, 2) void k_fb(
    const float* __restrict__ gp, const float* __restrict__ zbuf,
    const float* __restrict__ w2c, const float* __restrict__ ck,
    const float* __restrict__ vo, const float* __restrict__ ss,
    const float* __restrict__ cvr,
    const float* __restrict__ W1, const float* __restrict__ b1,
    const float* __restrict__ W2, const float* __restrict__ b2,
    const float* __restrict__ W3, const float* __restrict__ b3,
    const float* __restrict__ Wi, const float* __restrict__ bi,
    float* __restrict__ oA, float* __restrict__ oT,
    float* __restrict__ oI, float* __restrict__ oP, float* __restrict__ oM)
{
    __shared__ __align__(16) char lds[FB_TOT];
    float* sB2 = (float*)(lds + FB_B2);
    float* sBC = (float*)(lds + FB_BC);
    const float4* sW1 = (const float4*)(lds + FB_W1I);
    const int t = threadIdx.x, wv = t >> 6, l = t & 63, la = l & 15, lb = l >> 4;
    char* wlds = lds + FB_WV + wv * FB_WSZ;

    for (int idx = t; idx < 8192; idx += 512) {
        int k = idx >> 7, c = idx & 127;
        *(unsigned short*)(lds + FB_W2T + c*128 + (((k>>3) ^ (c&7))<<4) + (k&7)*2) = f2bf(W2[idx]);
    }
    for (int idx = t; idx < 12288; idx += 512) {
        int k = idx / 96, c = idx - k*96;
        *(unsigned short*)(lds + FB_W3T + c*256 + (((k>>3) ^ (c&15))<<4) + (k&7)*2) = f2bf(W3[idx]);
    }
    for (int idx = t; idx < 2304; idx += 512) {
        int c = idx / 24, k = idx - c*24;
        *(unsigned short*)(lds + FB_WIT + c*48 + k*2) = f2bf(Wi[k*96 + c]);
    }
    if (t < 128) sB2[t] = b2[t];
    if (t < 96)  sBC[t] = b3[t] + bi[t];
    if (t < 64)  ((float4*)(lds + FB_W1I))[t] = make_float4(W1[t], W1[64+t], b1[t], 0.f);

    const float R00=w2c[0],R01=w2c[1],R02=w2c[2],T0=w2c[3];
    const float R10=w2c[4],R11=w2c[5],R12=w2c[6],T1=w2c[7];
    const float R20=w2c[8],R21=w2c[9],R22=w2c[10],T2=w2c[11];
    const float k00=ck[0],k02=ck[2],k11=ck[4],k12=ck[5];
    const float n0=vo[0]+1e-3f, n1=vo[1]+1e-3f, n2=vo[2]+1e-3f;
    const float f0=vo[0]+ss[0]-1e-3f, f1=vo[1]+ss[1]-1e-3f, f2=vo[2]+ss[2]-1e-3f;
    const float cv0=cvr[0],cv1=cvr[1],cv2=cvr[2],cv3=cvr[3],cv4=cvr[4],cv5=cvr[5];
    const float i30=1.0f/(cv3-cv0), i41=1.0f/(cv4-cv1), i52=1.0f/(cv5-cv2);
    const float qtr = R00+R11+R22;
    const float qw = sqrtf(fmaxf(qtr+1.0f, 1e-8f))*0.5f;
    const float qi4 = 0.25f/qw;
    const float qx=(R21-R12)*qi4, qy=(R02-R20)*qi4, qz=(R10-R01)*qi4;
    __syncthreads();

    for (int n = blockIdx.x * 8 + wv; n < NCH; n += 2048) {
        const long Rb = (long)n * 64;
        const long R  = Rb + l;
        const float* g = gp + R * 25;
        float v[25];
        #pragma unroll
        for (int j = 0; j < 25; ++j) v[j] = g[j];
        const float x=v[0], y=v[1], zz=v[2];
        const float c0 = R00*x + R01*y + R02*zz + T0;
        const float c1 = R10*x + R11*y + R12*zz + T1;
        const float c2 = R20*x + R21*y + R22*zz + T2;
        bool m1 = c2 > 1e-6f;
        float zc = m1 ? c2 : 1e-6f;
        float fpx = k00*c0/zc + k02, fpy = k11*c1/zc + k12;
        bool m2 = (fpx>=0.f)&&(fpx<640.f)&&(fpy>=0.f)&&(fpy<480.f);
        bool gpm = (x>n0)&&(x<f0)&&(y>n1)&&(y<f1)&&(zz>n2)&&(zz<f2);
        bool mdet = m1 && m2 && gpm;
        float tag = (v[23]==1.0f) ? 0.5f : 0.0f;
        if (!mdet) tag = 1.0f;
        bool gm = (c0>=cv0)&&(c0<=cv3)&&(c1>=cv1)&&(c1<=cv4)&&(c2>=cv2)&&(c2<=cv5);
        bool reuse = gpm && gm;
        float mkf = reuse ? 1.0f : 0.0f;
        oM[R] = mkf; oT[R] = reuse ? tag : 0.0f;
        {
            float* pr = oP + R * 25;
            #pragma unroll
            for (int j = 0; j < 24; ++j) pr[j] = v[j];
            pr[24] = gpm ? 1.0f : v[24];
        }
        float czs = (fabsf(c2) < 1e-6f) ? 1e-6f : c2;
        float px = k00*c0/czs + k02, py = k11*c1/czs + k12;
        int ix = (int)fminf(fmaxf(px,0.f),639.f);
        int iy = (int)fminf(fmaxf(py,0.f),479.f);
        float d0 = zbuf[iy*640+ix], d1 = c2;
        float ar[23];
        if (reuse) {
            float p0=v[6],p1=v[7],p2=v[8],p3=v[9];
            ar[0]=sis((c0-cv0)*i30); ar[1]=sis((c1-cv1)*i41); ar[2]=sis((c2-cv2)*i52);
            ar[3]=sis(v[3]); ar[4]=sis(v[4]); ar[5]=sis(v[5]);
            ar[6]=qw*p0-qx*p1-qy*p2-qz*p3; ar[7]=qw*p1+qx*p0+qy*p3-qz*p2;
            ar[8]=qw*p2-qx*p3+qy*p0+qz*p1; ar[9]=qw*p3+qx*p2-qy*p1+qz*p0;
            ar[10]=sis(v[10]);
            #pragma unroll
            for (int j=0;j<12;++j) ar[11+j]=v[11+j];
        } else {
            #pragma unroll
            for (int j=0;j<23;++j) ar[j]=0.0f;
        }
        {
            float* aro = oA + R*23;
            #pragma unroll
            for (int j=0;j<23;++j) aro[j]=ar[j];
        }
        {
            char* anr = wlds + FB_ANB + l*48;
            uint4 u0,u1,u2;
            u0.x=cvtpk(ar[0],ar[1]); u0.y=cvtpk(ar[2],ar[3]); u0.z=cvtpk(ar[4],ar[5]); u0.w=cvtpk(ar[6],ar[7]);
            u1.x=cvtpk(ar[8],ar[9]); u1.y=cvtpk(ar[10],ar[11]); u1.z=cvtpk(ar[12],ar[13]); u1.w=cvtpk(ar[14],ar[15]);
            u2.x=cvtpk(ar[16],ar[17]); u2.y=cvtpk(ar[18],ar[19]); u2.z=cvtpk(ar[20],ar[21]); u2.w=cvtpk(ar[22],0.f);
            *(uint4*)(anr)=u0; *(uint4*)(anr+16)=u1; *(uint4*)(anr+32)=u2;
        }
        for (int s = 0; s < 4; ++s) {
            const int rsrc = 16*s + la;
            float d0s = __shfl(d0, rsrc), d1s = __shfl(d1, rsrc), mks = __shfl(mkf, rsrc);
            S8 hb0u, hb1u;
            {
                const int kb = lb*8;
                float h[8], h2[8];
                #pragma unroll
                for (int j=0;j<8;++j){ float4 w=sW1[kb+j]; h[j]=fmaxf(fmaf(d0s,w.x,fmaf(d1s,w.y,w.z)),0.f); }
                #pragma unroll
                for (int j=0;j<8;++j){ float4 w=sW1[32+kb+j]; h2[j]=fmaxf(fmaf(d0s,w.x,fmaf(d1s,w.y,w.z)),0.f); }
                hb0u.q.x=cvtpk(h[0],h[1]); hb0u.q.y=cvtpk(h[2],h[3]); hb0u.q.z=cvtpk(h[4],h[5]); hb0u.q.w=cvtpk(h[6],h[7]);
                hb1u.q.x=cvtpk(h2[0],h2[1]); hb1u.q.y=cvtpk(h2[2],h2[3]); hb1u.q.z=cvtpk(h2[4],h2[5]); hb1u.q.w=cvtpk(h2[6],h2[7]);
            }
            #pragma unroll
            for (int ct=0;ct<8;++ct){
                const int cc=ct*16+la;
                short8 w0=*(short8*)(lds+FB_W2T+cc*128+(((lb)^(cc&7))<<4));
                short8 w1v=*(short8*)(lds+FB_W2T+cc*128+(((lb+4)^(cc&7))<<4));
                f32x4 acc={0.f,0.f,0.f,0.f};
                acc=__builtin_amdgcn_mfma_f32_16x16x32_bf16(w0,hb0u.v,acc,0,0,0);
                acc=__builtin_amdgcn_mfma_f32_16x16x32_bf16(w1v,hb1u.v,acc,0,0,0);
                float4 bb=*(float4*)&sB2[ct*16+lb*4];
                uint2 pk; pk.x=cvtpk(fmaxf(acc[0]+bb.x,0.f),fmaxf(acc[1]+bb.y,0.f));
                pk.y=cvtpk(fmaxf(acc[2]+bb.z,0.f),fmaxf(acc[3]+bb.w,0.f));
                const int gg=ct*2+(lb>>1);
                *(uint2*)(wlds+FB_H2S+la*256+((gg^la)<<4)+(lb&1)*8)=pk;
            }
            {
                short8 B0=*(short8*)(wlds+FB_H2S+la*256+(((0+lb)^la)<<4));
                short8 B1=*(short8*)(wlds+FB_H2S+la*256+(((4+lb)^la)<<4));
                short8 B2v=*(short8*)(wlds+FB_H2S+la*256+(((8+lb)^la)<<4));
                short8 B3=*(short8*)(wlds+FB_H2S+la*256+(((12+lb)^la)<<4));
                short8 bA;
                if (lb<3) bA=*(short8*)(wlds+FB_ANB+rsrc*48+lb*16);
                else { S8 z; z.q=make_uint4(0,0,0,0); bA=z.v; }
                float* orow = oI + (Rb + rsrc)*96;
                #pragma unroll
                for (int ct=0;ct<6;++ct){
                    const int cc=ct*16+la;
                    f32x4 acc={0.f,0.f,0.f,0.f};
                    short8 A0=*(short8*)(lds+FB_W3T+cc*256+(((0+lb)^(cc&15))<<4));
                    short8 A1=*(short8*)(lds+FB_W3T+cc*256+(((4+lb)^(cc&15))<<4));
                    short8 A2=*(short8*)(lds+FB_W3T+cc*256+(((8+lb)^(cc&15))<<4));
                    short8 A3=*(short8*)(lds+FB_W3T+cc*256+(((12+lb)^(cc&15))<<4));
                    acc=__builtin_amdgcn_mfma_f32_16x16x32_bf16(A0,B0,acc,0,0,0);
                    acc=__builtin_amdgcn_mfma_f32_16x16x32_bf16(A1,B1,acc,0,0,0);
                    acc=__builtin_amdgcn_mfma_f32_16x16x32_bf16(A2,B2v,acc,0,0,0);
                    acc=__builtin_amdgcn_mfma_f32_16x16x32_bf16(A3,B3,acc,0,0,0);
                    short8 Aw;
                    if (lb<3) Aw=*(short8*)(lds+FB_WIT+cc*48+lb*16);
                    else { S8 z; z.q=make_uint4(0,0,0,0); Aw=z.v; }
                    acc=__builtin_amdgcn_mfma_f32_16x16x32_bf16(Aw,bA,acc,0,0,0);
                    float4 bb=*(float4*)&sBC[ct*16+lb*4];
                    float4 o;
                    o.x=(mks!=0.f)?acc[0]+bb.x:0.f; o.y=(mks!=0.f)?acc[1]+bb.y:0.f;
                    o.z=(mks!=0.f)?acc[2]+bb.z:0.f; o.w=(mks!=0.f)?acc[3]+bb.w:0.f;
                    *(float4*)(orow+ct*16+lb*4)=o;
                }
            }
        }
    }
}

extern "C" void kernel_launch(void* const* d_in, const int* in_sizes, int n_in,
                              void* d_out, int out_size, void* d_ws, size_t ws_size,
                              hipStream_t stream)
{
    const float* gp  = (const float*)d_in[0];
    const float* zb  = (const float*)d_in[2];
    const float* w2c = (const float*)d_in[3];
    const float* ck  = (const float*)d_in[4];
    const float* vo  = (const float*)d_in[5];
    const float* ss  = (const float*)d_in[6];
    const float* cvr = (const float*)d_in[7];
    const float* Wi  = (const float*)d_in[8];
    const float* bi  = (const float*)d_in[9];
    const float* W1  = (const float*)d_in[10];
    const float* b1  = (const float*)d_in[11];
    const float* W2  = (const float*)d_in[12];
    const float* b2  = (const float*)d_in[13];
    const float* W3  = (const float*)d_in[14];
    const float* b3  = (const float*)d_in[15];

    float* out = (float*)d_out;
    const long N = NG;
    float* oA = out;               // (N,23)
    float* oT = out + 23L * N;     // (N,)
    float* oI = out + 24L * N;     // (N,96)
    float* oP = out + 120L * N;    // (N,25)
    float* oM = out + 145L * N;    // (N,)

    const size_t need = 64L * NG + 256;
    if (ws_size >= need) {
        char* wpk = (char*)d_ws;
        int* ctr = (int*)((char*)d_ws + 64L * NG);
        hipMemsetAsync(ctr, 0, 4, stream);
        k_geom<<<NG / 256, 256, 0, stream>>>(gp, zb, w2c, ck, vo, ss, cvr,
                                             oA, oT, oP, oM, wpk);
        k_mlp<<<GRIDB, 512, 0, stream>>>(W1, b1, W2, b2, W3, b3, Wi, bi,
                                         wpk, oI, ctr);
    } else {
        k_fb<<<256, 512, 0, stream>>>(gp, zb, w2c, ck, vo, ss, cvr,
                                      W1, b1, W2, b2, W3, b3, Wi, bi,
                                      oA, oT, oI, oP, oM);
    }
}

// Round 9
// 208.701 us; speedup vs baseline: 1.2743x; 1.2743x over previous
//
#include <hip/hip_runtime.h>
#include <math.h>

#define NG 800000
#define NCH 12500        // 64-row chunks
#define GRID 256
#define BLK 512
#define NSTATIC 2048     // GRID * 8 waves

typedef __attribute__((ext_vector_type(8))) short short8;
typedef __attribute__((ext_vector_type(4))) float f32x4;
typedef float f4a __attribute__((ext_vector_type(4), aligned(4)));

// ---- shared LDS (bytes) ----
#define W2T_OFF 0        // 16384  [c=128][k=64] bf16 swz
#define W3T_OFF 16384    // 24576  [c=96][k=128] bf16 swz
#define WIT_OFF 40960    //  6144  [c=96][k=32]  bf16 swz (k>=23 zero)
#define B2_OFF  47104    //   512  f32[128]
#define BC_OFF  47616    //   384  f32[96]
#define WV_OFF  48128    // 8 waves x 12544
// per-wave region:
#define H2S0 0           //  4096  [16][128] bf16 swz (strip A)
#define H2S1 4096        //  4096  (strip B)
#define ANB  8192        //  4096  [64][32] bf16 swz
#define GPM  12288       //   256  f32[64] gp_mask
#define WV_SZ 12544
#define LDS_TOT (WV_OFF + 8 * WV_SZ)   // 148480

__device__ __forceinline__ float sis(float t) {
    t = fminf(fmaxf(t, 0.01f), 0.99f);
    return logf(t / (1.0f - t));
}
__device__ __forceinline__ unsigned short f2bf(float f) {
    unsigned int u = __float_as_uint(f);
    return (unsigned short)((u + 0x7FFFu + ((u >> 16) & 1u)) >> 16);
}
__device__ __forceinline__ unsigned int cvtpk(float a, float b) {
    unsigned int r;
    asm("v_cvt_pk_bf16_f32 %0, %1, %2" : "=v"(r) : "v"(a), "v"(b));
    return r;
}
union S8 { uint4 q; short8 v; };

__global__ __launch_bounds__(BLK, 2) void k_main(
    const float* __restrict__ gp,
    const float* __restrict__ zbuf,
    const float* __restrict__ w2c,
    const float* __restrict__ ck,
    const float* __restrict__ vo,
    const float* __restrict__ ss,
    const float* __restrict__ cvr,
    const float* __restrict__ W1, const float* __restrict__ b1,
    const float* __restrict__ W2, const float* __restrict__ b2,
    const float* __restrict__ W3, const float* __restrict__ b3,
    const float* __restrict__ Wi, const float* __restrict__ bi,
    float* __restrict__ oA, float* __restrict__ oT,
    float* __restrict__ oI, float* __restrict__ oP, float* __restrict__ oM,
    int* __restrict__ ctr, int usews)
{
    __shared__ __align__(16) char lds[LDS_TOT];
    float* sB2 = (float*)(lds + B2_OFF);
    float* sBC = (float*)(lds + BC_OFF);

    const int t   = threadIdx.x;
    const int wv  = t >> 6;
    const int l   = t & 63;
    const int la  = l & 15;
    const int lb  = l >> 4;
    char* wlds = lds + WV_OFF + wv * WV_SZ;
    float* sgpm = (float*)(wlds + GPM);

    // ---- shared weight images ----
    for (int idx = t; idx < 8192; idx += BLK) {            // W2T
        int k = idx >> 7, c = idx & 127;
        *(unsigned short*)(lds + W2T_OFF + c*128 + (((k>>3) ^ (c&7))<<4) + (k&7)*2)
            = f2bf(W2[idx]);
    }
    for (int idx = t; idx < 12288; idx += BLK) {           // W3T
        int k = idx / 96, c = idx - k*96;
        *(unsigned short*)(lds + W3T_OFF + c*256 + (((k>>3) ^ (c&15))<<4) + (k&7)*2)
            = f2bf(W3[idx]);
    }
    for (int idx = t; idx < 3072; idx += BLK) {            // WIT (swizzled, k>=23 zero)
        int c = idx >> 5, k = idx & 31;
        float val = (k < 23) ? Wi[k*96 + c] : 0.0f;
        *(unsigned short*)(lds + WIT_OFF + c*64 + (((k>>3) ^ (c&3))<<4) + (k&7)*2)
            = f2bf(val);
    }
    if (t < 128) sB2[t] = b2[t];
    if (t < 96)  sBC[t] = b3[t] + bi[t];

    // W1/b1 for this lane's 16 h1 columns (k = lb*8+j and 32+lb*8+j), in regs
    float w1x[16], w1y[16], w1z[16];
    #pragma unroll
    for (int j = 0; j < 8; ++j) {
        int k = lb*8 + j;
        w1x[j]   = W1[k];      w1y[j]   = W1[64+k];    w1z[j]   = b1[k];
        w1x[8+j] = W1[32+k];   w1y[8+j] = W1[96+k];    w1z[8+j] = b1[32+k];
    }

    // uniforms
    const float R00=w2c[0],R01=w2c[1],R02=w2c[2],T0=w2c[3];
    const float R10=w2c[4],R11=w2c[5],R12=w2c[6],T1=w2c[7];
    const float R20=w2c[8],R21=w2c[9],R22=w2c[10],T2=w2c[11];
    const float k00=ck[0],k02=ck[2],k11=ck[4],k12=ck[5];
    const float n0=vo[0]+1e-3f, n1=vo[1]+1e-3f, n2=vo[2]+1e-3f;
    const float f0=vo[0]+ss[0]-1e-3f, f1=vo[1]+ss[1]-1e-3f, f2=vo[2]+ss[2]-1e-3f;
    const float cv0=cvr[0],cv1=cvr[1],cv2=cvr[2],cv3=cvr[3],cv4=cvr[4],cv5=cvr[5];
    const float i30=1.0f/(cv3-cv0), i41=1.0f/(cv4-cv1), i52=1.0f/(cv5-cv2);
    const float qtr = R00 + R11 + R22;
    const float qw = sqrtf(fmaxf(qtr + 1.0f, 1e-8f)) * 0.5f;
    const float qi4 = 0.25f / qw;
    const float qx = (R21-R12)*qi4, qy=(R02-R20)*qi4, qz=(R10-R01)*qi4;

    __syncthreads();   // weights visible; only block barrier

    int n = blockIdx.x * 8 + wv;
    while (n < NCH) {
        const long Rb = (long)n * 64;
        const long R  = Rb + l;

        // ---- per-lane row load: 6 vec4 (4B-aligned) + 1 scalar ----
        const float* g = gp + R * 25;
        f4a q0 = *(const f4a*)(g);
        f4a q1 = *(const f4a*)(g + 4);
        f4a q2v= *(const f4a*)(g + 8);
        f4a q3 = *(const f4a*)(g + 12);
        f4a q4 = *(const f4a*)(g + 16);
        f4a q5 = *(const f4a*)(g + 20);
        float v24 = g[24];

        // ---- geometry ----
        const float x=q0.x, y=q0.y, zz=q0.z;
        const float c0 = R00*x + R01*y + R02*zz + T0;
        const float c1 = R10*x + R11*y + R12*zz + T1;
        const float c2 = R20*x + R21*y + R22*zz + T2;

        bool m1 = c2 > 1e-6f;
        float zc = m1 ? c2 : 1e-6f;
        float fpx = k00 * c0 / zc + k02;
        float fpy = k11 * c1 / zc + k12;
        bool m2 = (fpx >= 0.f) && (fpx < 640.f) && (fpy >= 0.f) && (fpy < 480.f);
        bool mall = m1 && m2;
        bool gpm = (x>n0)&&(x<f0)&&(y>n1)&&(y<f1)&&(zz>n2)&&(zz<f2);
        bool mdet = mall && gpm;
        float tag = (q5.w == 1.0f) ? 0.5f : 0.0f;
        if (!mdet) tag = 1.0f;
        bool gm = (c0>=cv0)&&(c0<=cv3)&&(c1>=cv1)&&(c1<=cv4)&&(c2>=cv2)&&(c2<=cv5);
        bool reuse = gpm && gm;
        float mkf = reuse ? 1.0f : 0.0f;

        oM[R] = mkf;
        oT[R] = reuse ? tag : 0.0f;
        sgpm[l] = gpm ? 1.0f : 0.0f;
        float v24n = gpm ? 1.0f : v24;   // keep lane copy too

        // df
        float czs = (fabsf(c2) < 1e-6f) ? 1e-6f : c2;
        float px = k00*c0/czs + k02;
        float py = k11*c1/czs + k12;
        int ix = (int)fminf(fmaxf(px, 0.f), 639.f);
        int iy = (int)fminf(fmaxf(py, 0.f), 479.f);
        float d0 = zbuf[iy*640 + ix];
        float d1 = c2;

        // anchor
        float a0,a1v,a2,a3,a4,a5,a6,a7,a8,a9,a10;
        float a11,a12,a13,a14,a15,a16,a17,a18,a19,a20,a21,a22;
        if (reuse) {
            float p0=q1.z, p1=q1.w, p2=q2v.x, p3=q2v.y;
            a0 = sis((c0 - cv0) * i30);
            a1v= sis((c1 - cv1) * i41);
            a2 = sis((c2 - cv2) * i52);
            a3 = sis(q0.w); a4 = sis(q1.x); a5 = sis(q1.y);
            a6 = qw*p0 - qx*p1 - qy*p2 - qz*p3;
            a7 = qw*p1 + qx*p0 + qy*p3 - qz*p2;
            a8 = qw*p2 - qx*p3 + qy*p0 + qz*p1;
            a9 = qw*p3 + qx*p2 - qy*p1 + qz*p0;
            a10 = sis(q2v.z);
            a11=q2v.w; a12=q3.x; a13=q3.y; a14=q3.z; a15=q3.w;
            a16=q4.x; a17=q4.y; a18=q4.z; a19=q4.w;
            a20=q5.x; a21=q5.y; a22=q5.z;
        } else {
            a0=a1v=a2=a3=a4=a5=a6=a7=a8=a9=a10=0.f;
            a11=a12=a13=a14=a15=a16=a17=a18=a19=a20=a21=a22=0.f;
        }

        // oA: 6 vec stores (overlap trick at 19)
        {
            float* aro = oA + R * 23;
            f4a s0 = {a0,a1v,a2,a3};   *(f4a*)(aro)      = s0;
            f4a s1 = {a4,a5,a6,a7};    *(f4a*)(aro + 4)  = s1;
            f4a s2 = {a8,a9,a10,a11};  *(f4a*)(aro + 8)  = s2;
            f4a s3 = {a12,a13,a14,a15};*(f4a*)(aro + 12) = s3;
            f4a s4 = {a16,a17,a18,a19};*(f4a*)(aro + 16) = s4;
            f4a s5 = {a19,a20,a21,a22};*(f4a*)(aro + 19) = s5;
        }

        // AN image: row l, 32 bf16 slots (k>=23 zero), 64B rows, swz
        {
            char* anr = wlds + ANB + l*64;
            uint4 u0, u1, u2, u3;
            u0.x=cvtpk(a0,a1v);  u0.y=cvtpk(a2,a3);   u0.z=cvtpk(a4,a5);   u0.w=cvtpk(a6,a7);
            u1.x=cvtpk(a8,a9);   u1.y=cvtpk(a10,a11); u1.z=cvtpk(a12,a13); u1.w=cvtpk(a14,a15);
            u2.x=cvtpk(a16,a17); u2.y=cvtpk(a18,a19); u2.z=cvtpk(a20,a21); u2.w=cvtpk(a22,0.f);
            u3.x=0u; u3.y=0u; u3.z=0u; u3.w=0u;
            *(uint4*)(anr + ((0 ^ (l&3))<<4)) = u0;
            *(uint4*)(anr + ((1 ^ (l&3))<<4)) = u1;
            *(uint4*)(anr + ((2 ^ (l&3))<<4)) = u2;
            *(uint4*)(anr + ((3 ^ (l&3))<<4)) = u3;
        }

        // ---- oP: coalesced float4 copy with col-24 patch from sgpm ----
        {
            const float4* gsrc = (const float4*)(gp + Rb * 25);
            float4* pdst = (float4*)(oP + Rb * 25);
            #pragma unroll
            for (int i = 0; i < 7; ++i) {
                int k = l + i*64;
                if (k < 400) {
                    float4 pv = gsrc[k];
                    int e0 = 4*k;
                    int j0 = 24 - (e0 % 25);
                    if (j0 < 4) {
                        int row = (e0 + j0) / 25;
                        if (sgpm[row] != 0.f) {
                            if (j0==0) pv.x = 1.f; else if (j0==1) pv.y = 1.f;
                            else if (j0==2) pv.z = 1.f; else pv.w = 1.f;
                        }
                    }
                    pdst[k] = pv;
                }
            }
        }

        // ---- 2 strip-pairs of 2x16 rows: weights read once per pair ----
        #pragma unroll
        for (int sp = 0; sp < 2; ++sp) {
            const int r0 = sp*32 + la;        // strip A data row
            const int r1 = sp*32 + 16 + la;   // strip B data row
            float d0a = __shfl(d0, r0), d1a = __shfl(d1, r0), mka = __shfl(mkf, r0);
            float d0b = __shfl(d0, r1), d1b = __shfl(d1, r1), mkb = __shfl(mkf, r1);

            // h1 fragments in-lane for both strips
            S8 ha0, ha1, hb0, hb1;
            {
                float h[16];
                #pragma unroll
                for (int j = 0; j < 16; ++j)
                    h[j] = fmaxf(fmaf(d0a, w1x[j], fmaf(d1a, w1y[j], w1z[j])), 0.f);
                ha0.q.x=cvtpk(h[0],h[1]);   ha0.q.y=cvtpk(h[2],h[3]);
                ha0.q.z=cvtpk(h[4],h[5]);   ha0.q.w=cvtpk(h[6],h[7]);
                ha1.q.x=cvtpk(h[8],h[9]);   ha1.q.y=cvtpk(h[10],h[11]);
                ha1.q.z=cvtpk(h[12],h[13]); ha1.q.w=cvtpk(h[14],h[15]);
                #pragma unroll
                for (int j = 0; j < 16; ++j)
                    h[j] = fmaxf(fmaf(d0b, w1x[j], fmaf(d1b, w1y[j], w1z[j])), 0.f);
                hb0.q.x=cvtpk(h[0],h[1]);   hb0.q.y=cvtpk(h[2],h[3]);
                hb0.q.z=cvtpk(h[4],h[5]);   hb0.q.w=cvtpk(h[6],h[7]);
                hb1.q.x=cvtpk(h[8],h[9]);   hb1.q.y=cvtpk(h[10],h[11]);
                hb1.q.z=cvtpk(h[12],h[13]); hb1.q.w=cvtpk(h[14],h[15]);
            }

            // GEMM1 (both strips share each weight read)
            #pragma unroll
            for (int ct = 0; ct < 8; ++ct) {
                const int cc = ct*16 + la;
                short8 w0 = *(short8*)(lds + W2T_OFF + cc*128 + (((lb  ) ^ (cc&7))<<4));
                short8 w1v= *(short8*)(lds + W2T_OFF + cc*128 + (((lb+4) ^ (cc&7))<<4));
                float4 bb = *(float4*)&sB2[ct*16 + lb*4];
                const int gg = ct*2 + (lb>>1);
                {
                    f32x4 acc = {0.f,0.f,0.f,0.f};
                    acc = __builtin_amdgcn_mfma_f32_16x16x32_bf16(w0, ha0.v, acc, 0, 0, 0);
                    acc = __builtin_amdgcn_mfma_f32_16x16x32_bf16(w1v, ha1.v, acc, 0, 0, 0);
                    uint2 pk;
                    pk.x = cvtpk(fmaxf(acc[0]+bb.x,0.f), fmaxf(acc[1]+bb.y,0.f));
                    pk.y = cvtpk(fmaxf(acc[2]+bb.z,0.f), fmaxf(acc[3]+bb.w,0.f));
                    *(uint2*)(wlds + H2S0 + la*256 + ((gg ^ la)<<4) + (lb&1)*8) = pk;
                }
                {
                    f32x4 acc = {0.f,0.f,0.f,0.f};
                    acc = __builtin_amdgcn_mfma_f32_16x16x32_bf16(w0, hb0.v, acc, 0, 0, 0);
                    acc = __builtin_amdgcn_mfma_f32_16x16x32_bf16(w1v, hb1.v, acc, 0, 0, 0);
                    uint2 pk;
                    pk.x = cvtpk(fmaxf(acc[0]+bb.x,0.f), fmaxf(acc[1]+bb.y,0.f));
                    pk.y = cvtpk(fmaxf(acc[2]+bb.z,0.f), fmaxf(acc[3]+bb.w,0.f));
                    *(uint2*)(wlds + H2S1 + la*256 + ((gg ^ la)<<4) + (lb&1)*8) = pk;
                }
            }

            // GEMM2 (both strips share each weight read)
            {
                short8 Ba0 = *(short8*)(wlds + H2S0 + la*256 + ((( 0 + lb) ^ la)<<4));
                short8 Ba1 = *(short8*)(wlds + H2S0 + la*256 + ((( 4 + lb) ^ la)<<4));
                short8 Ba2 = *(short8*)(wlds + H2S0 + la*256 + ((( 8 + lb) ^ la)<<4));
                short8 Ba3 = *(short8*)(wlds + H2S0 + la*256 + (((12 + lb) ^ la)<<4));
                short8 Bb0 = *(short8*)(wlds + H2S1 + la*256 + ((( 0 + lb) ^ la)<<4));
                short8 Bb1 = *(short8*)(wlds + H2S1 + la*256 + ((( 4 + lb) ^ la)<<4));
                short8 Bb2 = *(short8*)(wlds + H2S1 + la*256 + ((( 8 + lb) ^ la)<<4));
                short8 Bb3 = *(short8*)(wlds + H2S1 + la*256 + (((12 + lb) ^ la)<<4));
                short8 bAa = *(short8*)(wlds + ANB + r0*64 + ((lb ^ (r0&3))<<4));
                short8 bAb = *(short8*)(wlds + ANB + r1*64 + ((lb ^ (r1&3))<<4));
                float* orowa = oI + (Rb + r0) * 96;
                float* orowb = oI + (Rb + r1) * 96;
                #pragma unroll
                for (int ct = 0; ct < 6; ++ct) {
                    const int cc = ct*16 + la;
                    short8 A0 = *(short8*)(lds + W3T_OFF + cc*256 + ((( 0 + lb) ^ (cc&15))<<4));
                    short8 A1 = *(short8*)(lds + W3T_OFF + cc*256 + ((( 4 + lb) ^ (cc&15))<<4));
                    short8 A2 = *(short8*)(lds + W3T_OFF + cc*256 + ((( 8 + lb) ^ (cc&15))<<4));
                    short8 A3 = *(short8*)(lds + W3T_OFF + cc*256 + (((12 + lb) ^ (cc&15))<<4));
                    short8 Aw = *(short8*)(lds + WIT_OFF + cc*64 + ((lb ^ (cc&3))<<4));
                    float4 bb = *(float4*)&sBC[ct*16 + lb*4];
                    {
                        f32x4 acc = {0.f,0.f,0.f,0.f};
                        acc = __builtin_amdgcn_mfma_f32_16x16x32_bf16(A0, Ba0, acc, 0, 0, 0);
                        acc = __builtin_amdgcn_mfma_f32_16x16x32_bf16(A1, Ba1, acc, 0, 0, 0);
                        acc = __builtin_amdgcn_mfma_f32_16x16x32_bf16(A2, Ba2, acc, 0, 0, 0);
                        acc = __builtin_amdgcn_mfma_f32_16x16x32_bf16(A3, Ba3, acc, 0, 0, 0);
                        acc = __builtin_amdgcn_mfma_f32_16x16x32_bf16(Aw, bAa, acc, 0, 0, 0);
                        float4 o;
                        o.x = (mka != 0.f) ? acc[0] + bb.x : 0.f;
                        o.y = (mka != 0.f) ? acc[1] + bb.y : 0.f;
                        o.z = (mka != 0.f) ? acc[2] + bb.z : 0.f;
                        o.w = (mka != 0.f) ? acc[3] + bb.w : 0.f;
                        *(float4*)(orowa + ct*16 + lb*4) = o;
                    }
                    {
                        f32x4 acc = {0.f,0.f,0.f,0.f};
                        acc = __builtin_amdgcn_mfma_f32_16x16x32_bf16(A0, Bb0, acc, 0, 0, 0);
                        acc = __builtin_amdgcn_mfma_f32_16x16x32_bf16(A1, Bb1, acc, 0, 0, 0);
                        acc = __builtin_amdgcn_mfma_f32_16x16x32_bf16(A2, Bb2, acc, 0, 0, 0);
                        acc = __builtin_amdgcn_mfma_f32_16x16x32_bf16(A3, Bb3, acc, 0, 0, 0);
                        acc = __builtin_amdgcn_mfma_f32_16x16x32_bf16(Aw, bAb, acc, 0, 0, 0);
                        float4 o;
                        o.x = (mkb != 0.f) ? acc[0] + bb.x : 0.f;
                        o.y = (mkb != 0.f) ? acc[1] + bb.y : 0.f;
                        o.z = (mkb != 0.f) ? acc[2] + bb.z : 0.f;
                        o.w = (mkb != 0.f) ? acc[3] + bb.w : 0.f;
                        *(float4*)(orowb + ct*16 + lb*4) = o;
                    }
                }
            }
        }

        // ---- next chunk: work-stealing (disjoint chunks -> deterministic) ----
        if (usews) {
            int nn = 0;
            if (l == 0) nn = atomicAdd(ctr, 1);
            n = NSTATIC + __shfl(nn, 0);
        } else {
            n += NSTATIC;
        }
    }
}

extern "C" void kernel_launch(void* const* d_in, const int* in_sizes, int n_in,
                              void* d_out, int out_size, void* d_ws, size_t ws_size,
                              hipStream_t stream)
{
    const float* gp  = (const float*)d_in[0];
    const float* zb  = (const float*)d_in[2];
    const float* w2c = (const float*)d_in[3];
    const float* ck  = (const float*)d_in[4];
    const float* vo  = (const float*)d_in[5];
    const float* ss  = (const float*)d_in[6];
    const float* cvr = (const float*)d_in[7];
    const float* Wi  = (const float*)d_in[8];
    const float* bi  = (const float*)d_in[9];
    const float* W1  = (const float*)d_in[10];
    const float* b1  = (const float*)d_in[11];
    const float* W2  = (const float*)d_in[12];
    const float* b2  = (const float*)d_in[13];
    const float* W3  = (const float*)d_in[14];
    const float* b3  = (const float*)d_in[15];

    float* out = (float*)d_out;
    const long N = NG;
    float* oA = out;               // (N,23)
    float* oT = out + 23L * N;     // (N,)
    float* oI = out + 24L * N;     // (N,96)
    float* oP = out + 120L * N;    // (N,25)
    float* oM = out + 145L * N;    // (N,)

    int usews = (ws_size >= 4) ? 1 : 0;
    int* ctr = (int*)d_ws;
    if (usews) hipMemsetAsync(d_ws, 0, 4, stream);

    k_main<<<GRID, BLK, 0, stream>>>(gp, zb, w2c, ck, vo, ss, cvr,
                                     W1, b1, W2, b2, W3, b3, Wi, bi,
                                     oA, oT, oI, oP, oM, ctr, usews);
}

// Round 10
// 147.645 us; speedup vs baseline: 1.8013x; 1.4135x over previous
//
#include <hip/hip_runtime.h>
#include <math.h>

#define NG 800000        // = 12500 chunks of 64 rows
#define NCH 12500
#define GRID 256
#define BLK 512
#define WPB 8
#define NSTATIC 2048     // GRID * WPB

typedef __attribute__((ext_vector_type(8))) short short8;
typedef __attribute__((ext_vector_type(4))) float f32x4;

// ---- shared LDS layout (bytes) ----
#define W2T_OFF 0        // 16384  [c=128][k=64] bf16 swz
#define W3T_OFF 16384    // 24576  [c=96][k=128] bf16 swz
#define WIT_OFF 40960    //  6144  [c=96][k=32]  bf16 swz
#define B2_OFF  47104    //   512  f32[128]
#define BC_OFF  47616    //   384  f32[96]
#define WV_OFF  48128    // 8 waves x 11264
// per-wave region (11264 B):
#define X_OFF 0          //  6400  gp tile -> oA staging -> (H1S,H2S) in strips
#define H1S   0          //  alias: 2048  [16][64]  bf16 swz strip
#define H2S   2048       //  alias: 4096  [16][128] bf16 swz strip
#define ANB   6400       //  4096  [64][32] bf16 swz
#define DFP   10496      //   512  float2[64]
#define SMK   11008      //   256  float[64]
#define WV_SZ 11264
#define LDS_TOT (WV_OFF + WPB * WV_SZ)   // 138240

__device__ __forceinline__ float sis(float t) {
    t = fminf(fmaxf(t, 0.01f), 0.99f);
    return logf(t / (1.0f - t));
}
__device__ __forceinline__ unsigned short f2bf(float f) {
    unsigned int u = __float_as_uint(f);
    return (unsigned short)((u + 0x7FFFu + ((u >> 16) & 1u)) >> 16);
}
__device__ __forceinline__ unsigned int cvtpk(float a, float b) {
    unsigned int r;
    asm("v_cvt_pk_bf16_f32 %0, %1, %2" : "=v"(r) : "v"(a), "v"(b));
    return r;
}

__global__ __launch_bounds__(BLK, 2) void k_main(
    const float* __restrict__ gp,
    const float* __restrict__ zbuf,
    const float* __restrict__ w2c,
    const float* __restrict__ ck,
    const float* __restrict__ vo,
    const float* __restrict__ ss,
    const float* __restrict__ cvr,
    const float* __restrict__ W1, const float* __restrict__ b1,
    const float* __restrict__ W2, const float* __restrict__ b2,
    const float* __restrict__ W3, const float* __restrict__ b3,
    const float* __restrict__ Wi, const float* __restrict__ bi,
    float* __restrict__ oA, float* __restrict__ oT,
    float* __restrict__ oI, float* __restrict__ oP, float* __restrict__ oM)
{
    __shared__ __align__(16) char lds[LDS_TOT];
    float* sB2 = (float*)(lds + B2_OFF);
    float* sBC = (float*)(lds + BC_OFF);

    const int t   = threadIdx.x;
    const int wv  = t >> 6;
    const int l   = t & 63;
    const int la  = l & 15;
    const int lb  = l >> 4;
    const int sub = l & 3;
    char* wlds = lds + WV_OFF + wv * WV_SZ;
    float*  xf  = (float*)(wlds + X_OFF);
    float2* dfp = (float2*)(wlds + DFP);
    float*  smk = (float*)(wlds + SMK);

    // ---- build shared weight images (once per block) ----
    for (int idx = t; idx < 8192; idx += BLK) {            // W2T
        int k = idx >> 7, c = idx & 127;
        *(unsigned short*)(lds + W2T_OFF + c*128 + (((k>>3) ^ (c&7))<<4) + (k&7)*2)
            = f2bf(W2[idx]);
    }
    for (int idx = t; idx < 12288; idx += BLK) {           // W3T
        int k = idx / 96, c = idx - k*96;
        *(unsigned short*)(lds + W3T_OFF + c*256 + (((k>>3) ^ (c&15))<<4) + (k&7)*2)
            = f2bf(W3[idx]);
    }
    for (int idx = t; idx < 3072; idx += BLK) {            // WIT
        int c = idx >> 5, k = idx & 31;
        float val = (k < 23) ? Wi[k*96 + c] : 0.0f;
        *(unsigned short*)(lds + WIT_OFF + c*64 + (((k>>3) ^ (c&3))<<4) + (k&7)*2)
            = f2bf(val);
    }
    if (t < 128) sB2[t] = b2[t];
    if (t < 96)  sBC[t] = b3[t] + bi[t];

    // per-lane W1/b1 column block (cols sub*16..sub*16+15) in registers
    float4 w1a[4], w1b[4], b1r[4];
    #pragma unroll
    for (int gi = 0; gi < 4; ++gi) {
        w1a[gi] = *(const float4*)&W1[sub*16 + gi*4];
        w1b[gi] = *(const float4*)&W1[64 + sub*16 + gi*4];
        b1r[gi] = *(const float4*)&b1[sub*16 + gi*4];
    }

    // uniforms
    const float R00=w2c[0],R01=w2c[1],R02=w2c[2],T0=w2c[3];
    const float R10=w2c[4],R11=w2c[5],R12=w2c[6],T1=w2c[7];
    const float R20=w2c[8],R21=w2c[9],R22=w2c[10],T2=w2c[11];
    const float k00=ck[0],k02=ck[2],k11=ck[4],k12=ck[5];
    const float n0=vo[0]+1e-3f, n1=vo[1]+1e-3f, n2=vo[2]+1e-3f;
    const float f0=vo[0]+ss[0]-1e-3f, f1=vo[1]+ss[1]-1e-3f, f2=vo[2]+ss[2]-1e-3f;
    const float cv0=cvr[0],cv1=cvr[1],cv2=cvr[2],cv3=cvr[3],cv4=cvr[4],cv5=cvr[5];
    const float i30=1.0f/(cv3-cv0), i41=1.0f/(cv4-cv1), i52=1.0f/(cv5-cv2);
    const float qtr = R00 + R11 + R22;
    const float qw = sqrtf(fmaxf(qtr + 1.0f, 1e-8f)) * 0.5f;
    const float qi4 = 0.25f / qw;
    const float qx = (R21-R12)*qi4, qy=(R02-R20)*qi4, qz=(R10-R01)*qi4;

    __syncthreads();   // weight images visible; ONLY barrier in the kernel

    // ---- per-wave free-running loop over 64-row chunks ----
    for (int c = blockIdx.x * WPB + wv; c < NCH; c += NSTATIC) {
        const long Rb = (long)c * 64;
        const long R  = Rb + l;

        // -- stage gp tile: fully coalesced (400 float4), wave-private LDS --
        {
            const float4* g4 = (const float4*)(gp + Rb * 25);
            float4* x4 = (float4*)xf;
            #pragma unroll
            for (int i = 0; i < 7; ++i) {
                int k = l + i*64;
                if (k < 400) x4[k] = g4[k];
            }
        }

        // -- own row from LDS (conflict-free b32 reads) --
        float v[25];
        #pragma unroll
        for (int j = 0; j < 25; ++j) v[j] = xf[l*25 + j];

        // -- geometry --
        const float x=v[0], y=v[1], zz=v[2];
        const float c0 = R00*x + R01*y + R02*zz + T0;
        const float c1 = R10*x + R11*y + R12*zz + T1;
        const float c2 = R20*x + R21*y + R22*zz + T2;

        bool m1 = c2 > 1e-6f;
        float zc = m1 ? c2 : 1e-6f;
        float fpx = k00 * c0 / zc + k02;
        float fpy = k11 * c1 / zc + k12;
        bool m2 = (fpx >= 0.f) && (fpx < 640.f) && (fpy >= 0.f) && (fpy < 480.f);
        bool mall = m1 && m2;
        bool gpm = (x>n0)&&(x<f0)&&(y>n1)&&(y<f1)&&(zz>n2)&&(zz<f2);
        bool mdet = mall && gpm;
        float tag = (v[23] == 1.0f) ? 0.5f : 0.0f;
        if (!mdet) tag = 1.0f;
        bool gm = (c0>=cv0)&&(c0<=cv3)&&(c1>=cv1)&&(c1<=cv4)&&(c2>=cv2)&&(c2<=cv5);
        bool reuse = gpm && gm;

        oM[R] = reuse ? 1.0f : 0.0f;     // stride-4B: naturally coalesced
        oT[R] = reuse ? tag : 0.0f;
        smk[l] = reuse ? 1.0f : 0.0f;

        // df (fp32)
        float czs = (fabsf(c2) < 1e-6f) ? 1e-6f : c2;
        float px = k00*c0/czs + k02;
        float py = k11*c1/czs + k12;
        int ix = (int)fminf(fmaxf(px, 0.f), 639.f);
        int iy = (int)fminf(fmaxf(py, 0.f), 479.f);
        float d0g = zbuf[iy*640 + ix];
        dfp[l] = make_float2(d0g, c2);

        // -- patch col 24 in the LDS tile, then coalesced oP copy --
        xf[l*25 + 24] = gpm ? 1.0f : v[24];
        {
            float4* pd = (float4*)(oP + Rb * 25);
            const float4* x4 = (const float4*)xf;
            #pragma unroll
            for (int i = 0; i < 7; ++i) {
                int k = l + i*64;
                if (k < 400) pd[k] = x4[k];
            }
        }

        // -- anchor --
        float ar[23];
        if (reuse) {
            float p0=v[6], p1=v[7], p2=v[8], p3=v[9];
            ar[0] = sis((c0 - cv0) * i30);
            ar[1] = sis((c1 - cv1) * i41);
            ar[2] = sis((c2 - cv2) * i52);
            ar[3] = sis(v[3]); ar[4] = sis(v[4]); ar[5] = sis(v[5]);
            ar[6] = qw*p0 - qx*p1 - qy*p2 - qz*p3;
            ar[7] = qw*p1 + qx*p0 + qy*p3 - qz*p2;
            ar[8] = qw*p2 - qx*p3 + qy*p0 + qz*p1;
            ar[9] = qw*p3 + qx*p2 - qy*p1 + qz*p0;
            ar[10] = sis(v[10]);
            #pragma unroll
            for (int j = 0; j < 12; ++j) ar[11+j] = v[11+j];
        } else {
            #pragma unroll
            for (int j = 0; j < 23; ++j) ar[j] = 0.0f;
        }

        // -- anchors into LDS tile (overwrites gp tile), coalesced oA copy --
        #pragma unroll
        for (int j = 0; j < 23; ++j) xf[l*23 + j] = ar[j];
        {
            float4* ad = (float4*)(oA + Rb * 23);
            const float4* x4 = (const float4*)xf;
            #pragma unroll
            for (int i = 0; i < 6; ++i) {
                int k = l + i*64;
                if (k < 368) ad[k] = x4[k];
            }
        }

        // -- AN image: own row l, 32 cols bf16 (23 real), swizzled --
        {
            uint4 a0u, a1u, a2u, a3u;
            a0u.x=cvtpk(ar[0],ar[1]);   a0u.y=cvtpk(ar[2],ar[3]);
            a0u.z=cvtpk(ar[4],ar[5]);   a0u.w=cvtpk(ar[6],ar[7]);
            a1u.x=cvtpk(ar[8],ar[9]);   a1u.y=cvtpk(ar[10],ar[11]);
            a1u.z=cvtpk(ar[12],ar[13]); a1u.w=cvtpk(ar[14],ar[15]);
            a2u.x=cvtpk(ar[16],ar[17]); a2u.y=cvtpk(ar[18],ar[19]);
            a2u.z=cvtpk(ar[20],ar[21]); a2u.w=cvtpk(ar[22],0.0f);
            a3u.x=0u; a3u.y=0u; a3u.z=0u; a3u.w=0u;
            char* anr = wlds + ANB + l*64;
            *(uint4*)(anr + ((0 ^ (l&3))<<4)) = a0u;
            *(uint4*)(anr + ((1 ^ (l&3))<<4)) = a1u;
            *(uint4*)(anr + ((2 ^ (l&3))<<4)) = a2u;
            *(uint4*)(anr + ((3 ^ (l&3))<<4)) = a3u;
        }

        // ---- 4 strips of 16 rows: H1 -> GEMM1 -> GEMM2 ----
        for (int s = 0; s < 4; ++s) {
            // H1 strip: lane computes row (l>>2)'s cols sub*16..+15
            {
                const int rr = l >> 2;
                float2 dfv = dfp[16*s + rr];
                float h[16];
                #pragma unroll
                for (int gi = 0; gi < 4; ++gi) {
                    h[gi*4+0] = fmaxf(fmaf(dfv.x, w1a[gi].x, fmaf(dfv.y, w1b[gi].x, b1r[gi].x)), 0.f);
                    h[gi*4+1] = fmaxf(fmaf(dfv.x, w1a[gi].y, fmaf(dfv.y, w1b[gi].y, b1r[gi].y)), 0.f);
                    h[gi*4+2] = fmaxf(fmaf(dfv.x, w1a[gi].z, fmaf(dfv.y, w1b[gi].z, b1r[gi].z)), 0.f);
                    h[gi*4+3] = fmaxf(fmaf(dfv.x, w1a[gi].w, fmaf(dfv.y, w1b[gi].w, b1r[gi].w)), 0.f);
                }
                uint4 pa, pb;
                pa.x = cvtpk(h[0],h[1]);   pa.y = cvtpk(h[2],h[3]);
                pa.z = cvtpk(h[4],h[5]);   pa.w = cvtpk(h[6],h[7]);
                pb.x = cvtpk(h[8],h[9]);   pb.y = cvtpk(h[10],h[11]);
                pb.z = cvtpk(h[12],h[13]); pb.w = cvtpk(h[14],h[15]);
                char* h1r = wlds + H1S + rr*128;
                *(uint4*)(h1r + (((2*sub  ) ^ (rr&7))<<4)) = pa;
                *(uint4*)(h1r + (((2*sub+1) ^ (rr&7))<<4)) = pb;
            }

            // GEMM1: H2s[la][128] = relu(H1s[la] @ W2 + b2)
            {
                short8 hb0 = *(short8*)(wlds + H1S + la*128 + (((lb  ) ^ (la&7))<<4));
                short8 hb1 = *(short8*)(wlds + H1S + la*128 + (((lb+4) ^ (la&7))<<4));
                #pragma unroll
                for (int ct = 0; ct < 8; ++ct) {
                    const int cc = ct*16 + la;
                    short8 a0 = *(short8*)(lds + W2T_OFF + cc*128 + (((lb  ) ^ (cc&7))<<4));
                    short8 a1 = *(short8*)(lds + W2T_OFF + cc*128 + (((lb+4) ^ (cc&7))<<4));
                    f32x4 acc = {0.f, 0.f, 0.f, 0.f};
                    acc = __builtin_amdgcn_mfma_f32_16x16x32_bf16(a0, hb0, acc, 0, 0, 0);
                    acc = __builtin_amdgcn_mfma_f32_16x16x32_bf16(a1, hb1, acc, 0, 0, 0);
                    float4 bb = *(float4*)&sB2[ct*16 + lb*4];
                    float e0 = fmaxf(acc[0] + bb.x, 0.f);
                    float e1 = fmaxf(acc[1] + bb.y, 0.f);
                    float e2 = fmaxf(acc[2] + bb.z, 0.f);
                    float e3 = fmaxf(acc[3] + bb.w, 0.f);
                    uint2 pk; pk.x = cvtpk(e0, e1); pk.y = cvtpk(e2, e3);
                    const int gg = ct*2 + (lb>>1);
                    *(uint2*)(wlds + H2S + la*256 + ((gg ^ la)<<4) + (lb&1)*8) = pk;
                }
            }

            // GEMM2: oI rows 16s+la = H2s @ W3 + AN @ Wi + bc, masked
            {
                short8 B0 = *(short8*)(wlds + H2S + la*256 + ((( 0 + lb) ^ la)<<4));
                short8 B1 = *(short8*)(wlds + H2S + la*256 + ((( 4 + lb) ^ la)<<4));
                short8 B2v= *(short8*)(wlds + H2S + la*256 + ((( 8 + lb) ^ la)<<4));
                short8 B3 = *(short8*)(wlds + H2S + la*256 + (((12 + lb) ^ la)<<4));
                const int row = 16*s + la;
                short8 bA = *(short8*)(wlds + ANB + row*64 + ((lb ^ (row&3))<<4));
                float mk = smk[row];
                float* orow = oI + (Rb + row) * 96;
                #pragma unroll
                for (int ct = 0; ct < 6; ++ct) {
                    const int cc = ct*16 + la;
                    f32x4 acc = {0.f, 0.f, 0.f, 0.f};
                    short8 A0 = *(short8*)(lds + W3T_OFF + cc*256 + ((( 0 + lb) ^ (cc&15))<<4));
                    short8 A1 = *(short8*)(lds + W3T_OFF + cc*256 + ((( 4 + lb) ^ (cc&15))<<4));
                    short8 A2 = *(short8*)(lds + W3T_OFF + cc*256 + ((( 8 + lb) ^ (cc&15))<<4));
                    short8 A3 = *(short8*)(lds + W3T_OFF + cc*256 + (((12 + lb) ^ (cc&15))<<4));
                    acc = __builtin_amdgcn_mfma_f32_16x16x32_bf16(A0, B0, acc, 0, 0, 0);
                    acc = __builtin_amdgcn_mfma_f32_16x16x32_bf16(A1, B1, acc, 0, 0, 0);
                    acc = __builtin_amdgcn_mfma_f32_16x16x32_bf16(A2, B2v, acc, 0, 0, 0);
                    acc = __builtin_amdgcn_mfma_f32_16x16x32_bf16(A3, B3, acc, 0, 0, 0);
                    short8 Aw = *(short8*)(lds + WIT_OFF + cc*64 + ((lb ^ (cc&3))<<4));
                    acc = __builtin_amdgcn_mfma_f32_16x16x32_bf16(Aw, bA, acc, 0, 0, 0);
                    float4 bb = *(float4*)&sBC[ct*16 + lb*4];
                    float4 o;
                    o.x = (mk != 0.f) ? acc[0] + bb.x : 0.f;
                    o.y = (mk != 0.f) ? acc[1] + bb.y : 0.f;
                    o.z = (mk != 0.f) ? acc[2] + bb.z : 0.f;
                    o.w = (mk != 0.f) ? acc[3] + bb.w : 0.f;
                    *(float4*)(orow + ct*16 + lb*4) = o;
                }
            }
        }
    }
}

extern "C" void kernel_launch(void* const* d_in, const int* in_sizes, int n_in,
                              void* d_out, int out_size, void* d_ws, size_t ws_size,
                              hipStream_t stream)
{
    const float* gp  = (const float*)d_in[0];
    const float* zb  = (const float*)d_in[2];
    const float* w2c = (const float*)d_in[3];
    const float* ck  = (const float*)d_in[4];
    const float* vo  = (const float*)d_in[5];
    const float* ss  = (const float*)d_in[6];
    const float* cvr = (const float*)d_in[7];
    const float* Wi  = (const float*)d_in[8];
    const float* bi  = (const float*)d_in[9];
    const float* W1  = (const float*)d_in[10];
    const float* b1  = (const float*)d_in[11];
    const float* W2  = (const float*)d_in[12];
    const float* b2  = (const float*)d_in[13];
    const float* W3  = (const float*)d_in[14];
    const float* b3  = (const float*)d_in[15];

    float* out = (float*)d_out;
    const long N = NG;
    float* oA = out;               // (N,23)
    float* oT = out + 23L * N;     // (N,)
    float* oI = out + 24L * N;     // (N,96)
    float* oP = out + 120L * N;    // (N,25)
    float* oM = out + 145L * N;    // (N,)

    k_main<<<GRID, BLK, 0, stream>>>(gp, zb, w2c, ck, vo, ss, cvr,
                                     W1, b1, W2, b2, W3, b3, Wi, bi,
                                     oA, oT, oI, oP, oM);
}